// Round 7
// baseline (850.024 us; speedup 1.0000x reference)
//
#include <hip/hip_runtime.h>
#include <hip/hip_bf16.h>

#define H 4
#define D 256
#define NEG_SLOPE 0.2f

typedef __attribute__((ext_vector_type(8))) _Float16 f16x8;
typedef __attribute__((ext_vector_type(4))) _Float16 f16x4;
typedef __attribute__((ext_vector_type(4))) float f32x4;

// ---------------- f32 -> f16 convert (row-major, for W) ----------------
__global__ void k_cvt(const float* __restrict__ in, _Float16* __restrict__ out, int n4) {
    int i = blockIdx.x * blockDim.x + threadIdx.x;
    if (i >= n4) return;
    float4 v = ((const float4*)in)[i];
    f16x4 o = {(_Float16)v.x, (_Float16)v.y, (_Float16)v.z, (_Float16)v.w};
    *(f16x4*)&out[(size_t)i * 4] = o;
}

// ---- f32 x[N,128] -> 4 fp16 planes [4][Npad][32] ----
__global__ void k_cvt_x(const float* __restrict__ in, _Float16* __restrict__ xp,
                        size_t pstride, int n) {
    int i4 = blockIdx.x * blockDim.x + threadIdx.x;   // one float4 (4 cols)
    if (i4 >= n * 32) return;
    int row = i4 >> 5;
    int q   = i4 & 31;            // cols q*4..q*4+3
    float4 v = ((const float4*)in)[i4];
    f16x4 o = {(_Float16)v.x, (_Float16)v.y, (_Float16)v.z, (_Float16)v.w};
    int plane = q >> 3;
    int off   = (q & 7) * 4;
    *(f16x4*)&xp[(size_t)plane * pstride + (size_t)row * 32 + off] = o;
}

// ---- MFMA GEMM (fp16): h = x @ W^T from x planes; h/alpha written as planes ----
template<int K>
__global__ __launch_bounds__(256) void k_gemm_mfma(
        const _Float16* __restrict__ xp, size_t xpstride,
        const _Float16* __restrict__ wf,
        const float* __restrict__ att_src, const float* __restrict__ att_dst,
        _Float16* __restrict__ hp, size_t hpstride,
        float* __restrict__ asp, float* __restrict__ adp, size_t apstride,
        int nrows) {
    __shared__ _Float16 sx[64][40];
    __shared__ _Float16 sw[256][40];
    int t = threadIdx.x;
    int w = t >> 6, l = t & 63;
    int r = l & 15, q = l >> 4;
    int row0 = blockIdx.x * 64;
    f32x4 acc[16];
    #pragma unroll
    for (int cf = 0; cf < 16; ++cf) acc[cf] = (f32x4){0.f, 0.f, 0.f, 0.f};

    for (int k0 = 0; k0 < K; k0 += 32) {
        __syncthreads();
        // x tile: contiguous 4KB chunk of plane k0/32
        {
            const _Float16* xsrc = xp + (size_t)(k0 >> 5) * xpstride + (size_t)row0 * 32;
            uint4 v = *(const uint4*)(xsrc + (size_t)t * 8);
            *(uint4*)&sx[t >> 2][(t & 3) * 8] = v;
        }
        // W tile (256 x 32) from row-major [col][K]
        #pragma unroll
        for (int i = 0; i < 4; ++i) {
            int wr = (t >> 2) + i * 64;
            uint4 v = *(const uint4*)&wf[(size_t)wr * K + k0 + (t & 3) * 8];
            *(uint4*)&sw[wr][(t & 3) * 8] = v;
        }
        __syncthreads();
        f16x8 a = *(f16x8*)&sx[w * 16 + r][q * 8];
        #pragma unroll
        for (int cf = 0; cf < 16; ++cf) {
            f16x8 b = *(f16x8*)&sw[cf * 16 + r][q * 8];
            acc[cf] = __builtin_amdgcn_mfma_f32_16x16x32_f16(a, b, acc[cf], 0, 0, 0);
        }
    }
    // store h into planes: col=cf*16+r -> plane cf>>1, off (cf&1)*16+r
    #pragma unroll
    for (int cf = 0; cf < 16; ++cf) {
        _Float16* hpl = hp + (size_t)(cf >> 1) * hpstride;
        #pragma unroll
        for (int i = 0; i < 4; ++i) {
            int gr = row0 + w * 16 + q * 4 + i;
            if (gr < nrows)
                hpl[(size_t)gr * 32 + (cf & 1) * 16 + r] = (_Float16)acc[cf][i];
        }
    }
    // fused alpha epilogue -> planes [H][Npad]
    float asv[16], adv[16];
    #pragma unroll
    for (int cf = 0; cf < 16; ++cf) {
        asv[cf] = att_src[cf * 16 + r];
        adv[cf] = att_dst[cf * 16 + r];
    }
    #pragma unroll
    for (int i = 0; i < 4; ++i) {
        #pragma unroll
        for (int h4 = 0; h4 < 4; ++h4) {
            float ps = 0.f, pd = 0.f;
            #pragma unroll
            for (int j = 0; j < 4; ++j) {
                int cf = h4 * 4 + j;
                ps += acc[cf][i] * asv[cf];
                pd += acc[cf][i] * adv[cf];
            }
            #pragma unroll
            for (int m = 1; m < 16; m <<= 1) {
                ps += __shfl_xor(ps, m);
                pd += __shfl_xor(pd, m);
            }
            int gr = row0 + w * 16 + q * 4 + i;
            if (r == 0 && gr < nrows) {
                asp[(size_t)h4 * apstride + gr] = ps;
                adp[(size_t)h4 * apstride + gr] = pd;
            }
        }
    }
}

// ---------------- CSR build (graph constant across layers) ----------------
__global__ void k_deg(const int* __restrict__ ei, int E, int E2, int* __restrict__ deg) {
    int e = blockIdx.x * blockDim.x + threadIdx.x;
    if (e >= E2) return;
    int de = (e < E) ? ei[E + e] : (e - E);
    atomicAdd(&deg[de], 1);
}

__global__ void k_scan_block(const int* __restrict__ deg, int* __restrict__ incl,
                             int* __restrict__ bsum, int n) {
    __shared__ int sd[256];
    int t = threadIdx.x;
    int i = blockIdx.x * 256 + t;
    int v = (i < n) ? deg[i] : 0;
    sd[t] = v;
    __syncthreads();
    for (int off = 1; off < 256; off <<= 1) {
        int add = (t >= off) ? sd[t - off] : 0;
        __syncthreads();
        sd[t] += add;
        __syncthreads();
    }
    if (i < n) incl[i] = sd[t];
    if (t == 255) bsum[blockIdx.x] = sd[255];
}

__global__ void k_scan_bsum(int* __restrict__ bsum, int nb) {
    __shared__ int sd[256];
    int t = threadIdx.x;
    int v = (t < nb) ? bsum[t] : 0;
    sd[t] = v;
    __syncthreads();
    for (int off = 1; off < 256; off <<= 1) {
        int add = (t >= off) ? sd[t - off] : 0;
        __syncthreads();
        sd[t] += add;
        __syncthreads();
    }
    if (t < nb) bsum[t] = sd[t] - v;
}

__global__ void k_rowptr(const int* __restrict__ incl, const int* __restrict__ deg,
                         const int* __restrict__ boff, int* __restrict__ row_ptr,
                         int n, int total) {
    int i = blockIdx.x * blockDim.x + threadIdx.x;
    if (i < n) row_ptr[i] = incl[i] - deg[i] + boff[i >> 8];
    if (i == 0) row_ptr[n] = total;
}

__global__ void k_scatter(const int* __restrict__ ei, int E, int E2,
                          const int* __restrict__ row_ptr, int* __restrict__ cursor,
                          int* __restrict__ csr_src) {
    int e = blockIdx.x * blockDim.x + threadIdx.x;
    if (e >= E2) return;
    int se, de;
    if (e < E) { se = ei[e]; de = ei[E + e]; }
    else       { se = e - E; de = se; }
    int pos = atomicAdd(&cursor[de], 1);
    csr_src[row_ptr[de] + pos] = se;
}

// ---- per-(node,head): edge weights (CSR order) + softmax denominator ----
__global__ void k_edge(const int* __restrict__ row_ptr, const int* __restrict__ csr_src,
                       const float* __restrict__ asp, const float* __restrict__ adp,
                       size_t apstride, float* __restrict__ ew, float* __restrict__ sp,
                       int E2, int n) {
    int node = blockIdx.x * blockDim.x + threadIdx.x;
    if (node >= n) return;
    int hd = blockIdx.y;
    const float* aspp = asp + (size_t)hd * apstride;
    float ad = adp[(size_t)hd * apstride + node];
    float* ewp = ew + (size_t)hd * E2;
    int st = row_ptr[node], en = row_ptr[node + 1];
    float s = 0.f;
    for (int i = st; i < en; ++i) {
        float a = aspp[csr_src[i]] + ad;
        a = a > 0.f ? a : NEG_SLOPE * a;
        float w = __expf(a);
        ewp[i] = w;
        s += w;
    }
    sp[(size_t)hd * apstride + node] = s;
}

// ---- aggregation v3: channel-sliced, XCD-affine (cg = bid%8), wave per node ----
__global__ __launch_bounds__(256) void k_aggregate3(
        const _Float16* __restrict__ hp, size_t hpstride,
        const int* __restrict__ row_ptr, const int* __restrict__ csr_src,
        const float* __restrict__ ew, const float* __restrict__ sp, size_t apstride,
        const float* __restrict__ bias, float* __restrict__ outf,
        _Float16* __restrict__ outx, size_t xpstride,
        int E2, int relu, int nrows) {
    int bid = blockIdx.x;
    int cg = bid & 7;                      // channel group -> XCD (heuristic)
    int node = (bid >> 3) * 4 + (threadIdx.x >> 6);
    if (node >= nrows) return;
    int lane = threadIdx.x & 63;
    int half = lane >> 5;                  // which edge of the pair
    int c    = lane & 31;                  // channel within group
    int head = cg >> 1;
    const _Float16* hpl = hp + (size_t)cg * hpstride;
    const float* ewp = ew + (size_t)head * E2;
    int st = row_ptr[node], en = row_ptr[node + 1];
    int deg = en - st;
    float acc = 0.f;
    for (int b = 0; b < deg; b += 64) {
        int rem = deg - b; if (rem > 64) rem = 64;
        int li = st + b + (lane < rem ? lane : rem - 1);
        int myidx = csr_src[li];
        float myw = (lane < rem) ? ewp[li] : 0.f;
        for (int pb = 0; pb < rem; pb += 16) {
            int sn[8]; float w[8];
            #pragma unroll
            for (int p = 0; p < 8; ++p) {
                int e = pb + p * 2 + half;
                int sl = e < rem ? e : rem - 1;
                sn[p] = __shfl(myidx, sl);
                float ww = __shfl(myw, sl);
                w[p] = (e < rem) ? ww : 0.f;
            }
            _Float16 hv[8];
            #pragma unroll
            for (int p = 0; p < 8; ++p)
                hv[p] = hpl[(size_t)sn[p] * 32 + c];
            #pragma unroll
            for (int p = 0; p < 8; ++p)
                acc += w[p] * (float)hv[p];
        }
    }
    acc += __shfl_xor(acc, 32);            // combine the two edge-halves
    float sinv = 1.f / (sp[(size_t)head * apstride + node] + 1e-16f);
    float o = acc * sinv + bias[cg * 32 + c];
    if (relu) o = fmaxf(o, 0.f);
    if (half == 0) {
        if (outx) outx[(size_t)cg * xpstride + (size_t)node * 32 + c] = (_Float16)o;
        else      outf[(size_t)node * 256 + cg * 32 + c] = o;
    }
}

extern "C" void kernel_launch(void* const* d_in, const int* in_sizes, int n_in,
                              void* d_out, int out_size, void* d_ws, size_t ws_size,
                              hipStream_t stream) {
    const float* x = (const float*)d_in[0];
    const int* ei = (const int*)d_in[1];
    const int N  = in_sizes[0] / 128;   // 50000
    const int E  = in_sizes[1] / 2;     // 400000
    const int E2 = E + N;               // + self loops
    const int Npad = (N + 63) & ~63;    // 50048
    const size_t PST = (size_t)Npad * 32;   // fp16 plane stride (elems)
    const size_t AST = (size_t)Npad;        // f32 alpha/s plane stride

    char* wsp = (char*)d_ws;
    size_t off = 0;
    auto alloc = [&](size_t bytes) -> void* {
        void* p = wsp + off;
        off += (bytes + 255) & ~(size_t)255;
        return p;
    };
    _Float16* xp   = (_Float16*)alloc(8 * PST * 2);        // x planes (25.6 MB)
    _Float16* hp   = (_Float16*)alloc(8 * PST * 2);        // h planes (25.6 MB)
    _Float16* wf16 = (_Float16*)alloc((size_t)5 * D * D * 2);
    float* asp = (float*)alloc(4 * AST * 4);
    float* adp = (float*)alloc(4 * AST * 4);
    float* sp  = (float*)alloc(4 * AST * 4);
    float* ew  = (float*)alloc((size_t)4 * E2 * 4);        // 7.2 MB
    int* deg     = (int*)alloc((size_t)N * 4);
    int* incl    = (int*)alloc((size_t)N * 4);
    int* bsum    = (int*)alloc(256 * 4);
    int* row_ptr = (int*)alloc((size_t)(N + 1) * 4);
    int* cursor  = (int*)alloc((size_t)N * 4);
    int* csr_src = (int*)alloc((size_t)E2 * 4);
    (void)ws_size;

    hipMemsetAsync(deg, 0, (size_t)N * 4, stream);
    hipMemsetAsync(cursor, 0, (size_t)N * 4, stream);

    // convert x -> 4 planes; W -> fp16 row-major
    int nx4 = N * 32;
    k_cvt_x<<<(nx4 + 255) / 256, 256, 0, stream>>>(x, xp, PST, N);
    for (int l = 0; l < 5; ++l) {
        const float* W = (const float*)d_in[2 + 4 * l];
        int nw4 = D * (l == 0 ? 128 : 256) / 4;
        k_cvt<<<(nw4 + 255) / 256, 256, 0, stream>>>(W, wf16 + (size_t)l * D * D, nw4);
    }

    // CSR by dst
    int egrid = (E2 + 255) / 256;
    k_deg<<<egrid, 256, 0, stream>>>(ei, E, E2, deg);
    int nb = (N + 255) / 256;
    k_scan_block<<<nb, 256, 0, stream>>>(deg, incl, bsum, N);
    k_scan_bsum<<<1, 256, 0, stream>>>(bsum, nb);
    k_rowptr<<<nb, 256, 0, stream>>>(incl, deg, bsum, row_ptr, N, E2);
    k_scatter<<<egrid, 256, 0, stream>>>(ei, E, E2, row_ptr, cursor, csr_src);

    int ggrid = (N + 63) / 64;
    int agrid = ((N + 3) / 4) * 8;                 // chunks x 8 channel-groups
    dim3 eg((N + 255) / 256, H);
    for (int l = 0; l < 5; ++l) {
        const float* as_ = (const float*)d_in[3 + 4 * l];
        const float* ad_ = (const float*)d_in[4 + 4 * l];
        const float* bs_ = (const float*)d_in[5 + 4 * l];
        const _Float16* wl = wf16 + (size_t)l * D * D;

        if (l == 0)
            k_gemm_mfma<128><<<ggrid, 256, 0, stream>>>(xp, PST, wl, as_, ad_,
                                                        hp, PST, asp, adp, AST, N);
        else
            k_gemm_mfma<256><<<ggrid, 256, 0, stream>>>(xp, PST, wl, as_, ad_,
                                                        hp, PST, asp, adp, AST, N);

        k_edge<<<eg, 256, 0, stream>>>(row_ptr, csr_src, asp, adp, AST, ew, sp, E2, N);

        int last = (l == 4);
        k_aggregate3<<<agrid, 256, 0, stream>>>(hp, PST, row_ptr, csr_src, ew, sp, AST,
                                                bs_, last ? (float*)d_out : nullptr,
                                                last ? nullptr : xp, PST,
                                                E2, last ? 0 : 1, N);
    }
}